// Round 4
// baseline (34.479 us; speedup 1.0000x reference)
//
#include <hip/hip_runtime.h>
#include <math.h>

#define B_    32
#define PPB   256
#define N_    (B_*PPB)     // 8192 proposals / padded slots
#define M_    128
#define LANG_ 256
#define H_    128
#define EPS_  1e-5f
#define MC    32           // columns per MLP block

typedef __attribute__((ext_vector_type(8))) short s16x8;
typedef __attribute__((ext_vector_type(4))) float f32x4;

static __device__ __forceinline__ unsigned short f2bf(float x) {
  unsigned int u = __float_as_uint(x);
  unsigned int r = (u + 0x7fff + ((u >> 16) & 1)) >> 16;
  return (unsigned short)r;
}
static __device__ __forceinline__ float bf2f(unsigned short h) {
  return __uint_as_float(((unsigned int)h) << 16);
}

// ---------------------------------------------------------------------------
// Kernel A: batch id + within-chunk stable rank (ballot-based) + chunk
// histograms + fused lang projection. One block per 256-proposal chunk.
// ---------------------------------------------------------------------------
__global__ __launch_bounds__(256) void k_map_a(
    const int* __restrict__ pidx, const int* __restrict__ poff,
    const int* __restrict__ boff, int* __restrict__ bid_g,
    int* __restrict__ wrank_g, int* __restrict__ hist_g,
    int* __restrict__ src_of_dest,
    const float* __restrict__ Wf, const float* __restrict__ lang,
    float* __restrict__ lp)
{
  __shared__ int sb[33];
  __shared__ int wh[4][32];    // per-wave per-bin counts
  const int tid = threadIdx.x;
  const int i = blockIdx.x * 256 + tid;
  const int lane = tid & 63, wid = tid >> 6;
  if (tid < 33) sb[tid] = boff[tid];
  __syncthreads();
  const int off = poff[i];
  const int fp  = pidx[2 * off + 1];
  int cnt = 0;
  #pragma unroll
  for (int j = 0; j < 33; ++j) cnt += (sb[j] <= fp) ? 1 : 0;
  int bd = cnt - 1;
  bd = bd < 0 ? 0 : (bd > 31 ? 31 : bd);
  bid_g[i] = bd;
  src_of_dest[i] = -1;

  // ballot-based within-chunk stable rank
  unsigned long long mym = 0;
  #pragma unroll
  for (int k = 0; k < 32; ++k) {
    const unsigned long long m = __ballot(bd == k);
    if (bd == k) mym = m;
    if (lane == k) wh[wid][k] = __popcll(m);
  }
  const int rw = __popcll(mym & ((1ull << lane) - 1ull));
  __syncthreads();
  int base = 0;
  #pragma unroll
  for (int w = 0; w < 4; ++w) if (w < wid) base += wh[w][bd];
  wrank_g[i] = base + rw;
  if (tid < 32) hist_g[blockIdx.x * 32 + tid] =
      wh[0][tid] + wh[1][tid] + wh[2][tid] + wh[3][tid];

  // fused lang projection (batch = blockIdx.x)
  if (tid < 128) {
    const int o = tid;
    float acc = 0.f;
    for (int l = 0; l < LANG_; l += 4) {
      const float4 w = *reinterpret_cast<const float4*>(Wf + o * 384 + 128 + l);
      const float4 e = *reinterpret_cast<const float4*>(lang + blockIdx.x * LANG_ + l);
      acc += w.x * e.x + w.y * e.y + w.z * e.z + w.w * e.w;
    }
    lp[blockIdx.x * H_ + o] = acc;
  }
}

// ---------------------------------------------------------------------------
// Kernel B: cross-chunk exclusive scan per bin + scatter inverse map.
// ---------------------------------------------------------------------------
__global__ __launch_bounds__(1024) void k_map_b(
    const int* __restrict__ bid_g, const int* __restrict__ wrank_g,
    const int* __restrict__ hist_g, int* __restrict__ src_of_dest)
{
  __shared__ int cb[32][32];
  const int tid = threadIdx.x;
  if (tid < 32) {
    int run = 0;
    for (int c = 0; c < 32; ++c) { cb[c][tid] = run; run += hist_g[c * 32 + tid]; }
  }
  __syncthreads();
  #pragma unroll
  for (int k = 0; k < 8; ++k) {
    const int i = tid * 8 + k;
    const int bd = bid_g[i];
    const int rank = cb[i >> 8][bd] + wrank_g[i];
    if (rank < PPB) src_of_dest[bd * PPB + rank] = i;
  }
}

// ---------------------------------------------------------------------------
// Kernel D: MFMA MLP. 256 blocks x 256 threads, 32 columns per block.
// hi/lo bf16 split, 2 K=256 passes per layer (exact (Whi+Wlo)(Xhi+Xlo)).
// Weights converted in-register from ORIGINAL fp32 arrays (clean LLC lines,
// no dirty cross-XCD coherence); next layer prefetched before current MFMAs.
// ---------------------------------------------------------------------------
__global__ __launch_bounds__(256, 1) void k_mlp(
    const float* __restrict__ feats,
    const float* __restrict__ Wf, const float* __restrict__ W1,
    const float* __restrict__ W2,
    const float* __restrict__ bf, const float* __restrict__ b1,
    const float* __restrict__ g1, const float* __restrict__ be1,
    const float* __restrict__ rm1, const float* __restrict__ rv1,
    const float* __restrict__ b2, const float* __restrict__ g2,
    const float* __restrict__ be2, const float* __restrict__ rm2,
    const float* __restrict__ rv2,
    const float* __restrict__ W3, const float* __restrict__ b3,
    const int* __restrict__ src_of_dest, const float* __restrict__ lpg,
    float* __restrict__ out)
{
  __shared__ s16x8 XbHi[512];      // [s4][g4][n32] 16B frags  (8 KB)
  __shared__ s16x8 XbLo[512];      //                           (8 KB)
  __shared__ float pbuf[1024];     // 8 x 128 params            (4 KB)
  __shared__ float outp[128];

  const int tid = threadIdx.x;
  const int lane = tid & 63, wid = tid >> 6;
  const int q0 = blockIdx.x * MC;
  const int b = blockIdx.x >> 3;   // 8 blocks per batch
  const int o16 = lane & 15, g = lane >> 4;

  // ---- prefetch layer-0 fp32 weights into regs (issued first, latency
  //      hides under pbuf + feats staging)
  float4 wstage[16];               // [t*8 + sp*2 + half]
  #pragma unroll
  for (int t = 0; t < 2; ++t) {
    const int o = (wid * 2 + t) * 16 + o16;
    #pragma unroll
    for (int sp = 0; sp < 4; ++sp) {
      const float* rp = Wf + (size_t)o * 384 + sp * 32 + g * 4;
      wstage[t * 8 + sp * 2]     = *reinterpret_cast<const float4*>(rp);
      wstage[t * 8 + sp * 2 + 1] = *reinterpret_cast<const float4*>(rp + 16);
    }
  }

  // ---- params into LDS (BN folded here): [0]=bf+lp, [1]=b1,[2]=s1,[3]=t1,
  //      [4]=b2,[5]=s2,[6]=t2,[7]=W3
  #pragma unroll
  for (int j = tid; j < 1024; j += 256) {
    const int arr = j >> 7, o = j & 127;
    float v;
    switch (arr) {
      case 0: v = bf[o] + lpg[b * H_ + o]; break;
      case 1: v = b1[o]; break;
      case 2: v = g1[o] * rsqrtf(rv1[o] + EPS_); break;
      case 3: { const float s = g1[o] * rsqrtf(rv1[o] + EPS_);
                v = be1[o] - rm1[o] * s; } break;
      case 4: v = b2[o]; break;
      case 5: v = g2[o] * rsqrtf(rv2[o] + EPS_); break;
      case 6: { const float s = g2[o] * rsqrtf(rv2[o] + EPS_);
                v = be2[o] - rm2[o] * s; } break;
      default: v = W3[o]; break;
    }
    pbuf[j] = v;
  }

  // ---- stage gathered feats (hi/lo split) into Xb
  {
    const int n = tid & 31, u = tid >> 5;
    const int srow = src_of_dest[q0 + n];
    #pragma unroll
    for (int it = 0; it < 2; ++it) {
      const int sg = u + 8 * it, s = sg >> 2, gg = sg & 3;
      const int k0 = s * 32 + gg * 4;
      float4 a = make_float4(0.f, 0.f, 0.f, 0.f), bq = a;
      if (srow >= 0) {
        a  = *reinterpret_cast<const float4*>(feats + (size_t)srow * M_ + k0);
        bq = *reinterpret_cast<const float4*>(feats + (size_t)srow * M_ + k0 + 16);
      }
      const float av[8] = {a.x, a.y, a.z, a.w, bq.x, bq.y, bq.z, bq.w};
      s16x8 hv, lv;
      #pragma unroll
      for (int e = 0; e < 8; ++e) {
        const unsigned short h = f2bf(av[e]);
        hv[e] = (short)h;
        lv[e] = (short)f2bf(av[e] - bf2f(h));
      }
      XbHi[(s * 4 + gg) * 32 + n] = hv;
      XbLo[(s * 4 + gg) * 32 + n] = lv;
    }
  }
  __syncthreads();

  // ---- convert layer-0 weights into A-frags
  s16x8 A_[2][8];
  #pragma unroll
  for (int t = 0; t < 2; ++t)
    #pragma unroll
    for (int sp = 0; sp < 4; ++sp) {
      const float4 a = wstage[t * 8 + sp * 2], c = wstage[t * 8 + sp * 2 + 1];
      const float av[8] = {a.x, a.y, a.z, a.w, c.x, c.y, c.z, c.w};
      s16x8 hv, lv;
      #pragma unroll
      for (int e = 0; e < 8; ++e) {
        const unsigned short h = f2bf(av[e]);
        hv[e] = (short)h;
        lv[e] = (short)f2bf(av[e] - bf2f(h));
      }
      A_[t][sp] = hv;
      A_[t][4 + sp] = lv;
    }

  for (int L = 0; L < 3; ++L) {
    // B-frags from LDS into regs
    s16x8 Bh[4][2], Bl[4][2];
    #pragma unroll
    for (int s = 0; s < 4; ++s)
      #pragma unroll
      for (int nt = 0; nt < 2; ++nt) {
        const int idx = (s * 4 + g) * 32 + nt * 16 + o16;
        Bh[s][nt] = XbHi[idx];
        Bl[s][nt] = XbLo[idx];
      }
    __syncthreads();   // all waves done reading Xb before anyone overwrites

    // prefetch next layer fp32 weights (issues before the MFMA wall)
    if (L < 2) {
      const float* Wn = (L == 0) ? W1 : W2;
      #pragma unroll
      for (int t = 0; t < 2; ++t) {
        const int o = (wid * 2 + t) * 16 + o16;
        #pragma unroll
        for (int sp = 0; sp < 4; ++sp) {
          const float* rp = Wn + (size_t)o * H_ + sp * 32 + g * 4;
          wstage[t * 8 + sp * 2]     = *reinterpret_cast<const float4*>(rp);
          wstage[t * 8 + sp * 2 + 1] = *reinterpret_cast<const float4*>(rp + 16);
        }
      }
    }

    f32x4 acc[2][2];
    #pragma unroll
    for (int t = 0; t < 2; ++t)
      #pragma unroll
      for (int nt = 0; nt < 2; ++nt)
        acc[t][nt] = (f32x4){0.f, 0.f, 0.f, 0.f};

    // pass 1: [Whi|Wlo] . [Xhi;Xlo]
    #pragma unroll
    for (int sg = 0; sg < 8; ++sg)
      #pragma unroll
      for (int nt = 0; nt < 2; ++nt) {
        const s16x8 bb = (sg < 4) ? Bh[sg][nt] : Bl[sg - 4][nt];
        #pragma unroll
        for (int t = 0; t < 2; ++t)
          acc[t][nt] = __builtin_amdgcn_mfma_f32_16x16x32_bf16(
              A_[t][sg], bb, acc[t][nt], 0, 0, 0);
      }
    // pass 2: [Whi|Wlo] . [Xlo;Xhi]
    #pragma unroll
    for (int sg = 0; sg < 8; ++sg)
      #pragma unroll
      for (int nt = 0; nt < 2; ++nt) {
        const s16x8 bb = (sg < 4) ? Bl[sg][nt] : Bh[sg - 4][nt];
        #pragma unroll
        for (int t = 0; t < 2; ++t)
          acc[t][nt] = __builtin_amdgcn_mfma_f32_16x16x32_bf16(
              A_[t][sg], bb, acc[t][nt], 0, 0, 0);
      }

    if (L < 2) {
      // activation + split + write next-layer Xb (wave wid owns s=wid)
      #pragma unroll
      for (int nt = 0; nt < 2; ++nt) {
        s16x8 hv, lv;
        #pragma unroll
        for (int t = 0; t < 2; ++t)
          #pragma unroll
          for (int r = 0; r < 4; ++r) {
            const int o = (wid * 2 + t) * 16 + g * 4 + r;
            const float z = acc[t][nt][r];
            float v;
            if (L == 0) v = fmaxf(z + pbuf[o], 0.f);
            else        v = fmaxf(z + pbuf[128 + o], 0.f) * pbuf[256 + o] + pbuf[384 + o];
            const unsigned short h = f2bf(v);
            hv[t * 4 + r] = (short)h;
            lv[t * 4 + r] = (short)f2bf(v - bf2f(h));
          }
        const int widx = (wid * 4 + g) * 32 + nt * 16 + o16;
        XbHi[widx] = hv;
        XbLo[widx] = lv;
      }
      __syncthreads();

      // convert prefetched next-layer weights into A-frags
      #pragma unroll
      for (int t = 0; t < 2; ++t)
        #pragma unroll
        for (int sp = 0; sp < 4; ++sp) {
          const float4 a = wstage[t * 8 + sp * 2], c = wstage[t * 8 + sp * 2 + 1];
          const float av[8] = {a.x, a.y, a.z, a.w, c.x, c.y, c.z, c.w};
          s16x8 hv, lv;
          #pragma unroll
          for (int e = 0; e < 8; ++e) {
            const unsigned short h = f2bf(av[e]);
            hv[e] = (short)h;
            lv[e] = (short)f2bf(av[e] - bf2f(h));
          }
          A_[t][sp] = hv;
          A_[t][4 + sp] = lv;
        }
    } else {
      // final: BN2 then dot with W3, reduce over chan groups
      float p0 = 0.f, p1 = 0.f;
      #pragma unroll
      for (int t = 0; t < 2; ++t)
        #pragma unroll
        for (int r = 0; r < 4; ++r) {
          const int o = (wid * 2 + t) * 16 + g * 4 + r;
          const float w3 = pbuf[896 + o];
          const float bb2 = pbuf[512 + o], ss2 = pbuf[640 + o], tt2 = pbuf[768 + o];
          p0 += w3 * (fmaxf(acc[t][0][r] + bb2, 0.f) * ss2 + tt2);
          p1 += w3 * (fmaxf(acc[t][1][r] + bb2, 0.f) * ss2 + tt2);
        }
      p0 += __shfl_xor(p0, 16); p0 += __shfl_xor(p0, 32);
      p1 += __shfl_xor(p1, 16); p1 += __shfl_xor(p1, 32);
      if (lane < 16) {
        outp[wid * 32 + lane] = p0;
        outp[wid * 32 + 16 + lane] = p1;
      }
      __syncthreads();
      if (tid < 32)
        out[q0 + tid] = outp[tid] + outp[32 + tid] + outp[64 + tid] + outp[96 + tid] + b3[0];
    }
  }
}

// ---------------------------------------------------------------------------
extern "C" void kernel_launch(void* const* d_in, const int* in_sizes, int n_in,
                              void* d_out, int out_size, void* d_ws, size_t ws_size,
                              hipStream_t stream) {
  const float* feats = (const float*)d_in[0];
  const int*   pidx  = (const int*)d_in[1];
  const int*   poff  = (const int*)d_in[2];
  const int*   boff  = (const int*)d_in[3];
  const float* lang  = (const float*)d_in[4];
  const float* Wf    = (const float*)d_in[5];
  const float* bf    = (const float*)d_in[6];
  const float* W1    = (const float*)d_in[7];
  const float* b1    = (const float*)d_in[8];
  const float* g1    = (const float*)d_in[9];
  const float* be1   = (const float*)d_in[10];
  const float* rm1   = (const float*)d_in[11];
  const float* rv1   = (const float*)d_in[12];
  const float* W2    = (const float*)d_in[13];
  const float* b2    = (const float*)d_in[14];
  const float* g2    = (const float*)d_in[15];
  const float* be2   = (const float*)d_in[16];
  const float* rm2   = (const float*)d_in[17];
  const float* rv2   = (const float*)d_in[18];
  const float* W3    = (const float*)d_in[19];
  const float* b3    = (const float*)d_in[20];
  float* out = (float*)d_out;

  int* srcmap = (int*)d_ws;                  // 32768 B
  int* bidp   = srcmap + N_;                 // 32768 B
  int* wrank  = bidp + N_;                   // 32768 B
  int* hist   = wrank + N_;                  // 4096 B
  float* lp = (float*)(hist + 32 * 32);      // 16384 B

  hipLaunchKernelGGL(k_map_a, dim3(32), dim3(256), 0, stream,
                     pidx, poff, boff, bidp, wrank, hist, srcmap, Wf, lang, lp);
  hipLaunchKernelGGL(k_map_b, dim3(1), dim3(1024), 0, stream,
                     bidp, wrank, hist, srcmap);
  hipLaunchKernelGGL(k_mlp, dim3(N_ / MC), dim3(256), 0, stream,
                     feats, Wf, W1, W2, bf, b1, g1, be1, rm1, rv1,
                     b2, g2, be2, rm2, rv2, W3, b3, srcmap, lp, out);
}